// Round 7
// baseline (251.286 us; speedup 1.0000x reference)
//
#include <hip/hip_runtime.h>

#define NROWS   4194304
#define NBLK    2048                      // NROWS / (256 thr * 8 rows), exact
#define INV_B   (1.0f / 4194304.0f)
#define LOG2E   1.44269504088896340736f
#define LN2     0.69314718055994530942f

// v_exp_f32: 2^x ; v_log_f32: log2(x) — raw builtins avoid glibc name clash.
#define EXP2F(x) __builtin_amdgcn_exp2f(x)
#define LOG2F(x) __builtin_amdgcn_logf(x)

// One row, all-scalar (register-resident). exp2-domain softmax, x[t] via
// cndmask chain, argmax==3 as 4 compares (first-occurrence exact:
// a3>=m proves a3 is a max; a3>a0..a2 proves no earlier max).
__device__ __forceinline__ void row10(float a0, float a1, float a2, float a3,
                                      float a4, float a5, float a6, float a7,
                                      float a8, float a9, int t,
                                      float& nll_acc, int& flag_acc) {
    const float m = fmaxf(fmaxf(fmaxf(fmaxf(a0, a1), fmaxf(a2, a3)),
                                fmaxf(fmaxf(a4, a5), fmaxf(a6, a7))),
                          fmaxf(a8, a9));
    const float c = -m * LOG2E;
    float s;
    s  = EXP2F(__builtin_fmaf(a0, LOG2E, c));
    s += EXP2F(__builtin_fmaf(a1, LOG2E, c));
    s += EXP2F(__builtin_fmaf(a2, LOG2E, c));
    s += EXP2F(__builtin_fmaf(a3, LOG2E, c));
    s += EXP2F(__builtin_fmaf(a4, LOG2E, c));
    s += EXP2F(__builtin_fmaf(a5, LOG2E, c));
    s += EXP2F(__builtin_fmaf(a6, LOG2E, c));
    s += EXP2F(__builtin_fmaf(a7, LOG2E, c));
    s += EXP2F(__builtin_fmaf(a8, LOG2E, c));
    s += EXP2F(__builtin_fmaf(a9, LOG2E, c));
    float xt = a0;
    xt = (t == 1) ? a1 : xt;  xt = (t == 2) ? a2 : xt;  xt = (t == 3) ? a3 : xt;
    xt = (t == 4) ? a4 : xt;  xt = (t == 5) ? a5 : xt;  xt = (t == 6) ? a6 : xt;
    xt = (t == 7) ? a7 : xt;  xt = (t == 8) ? a8 : xt;  xt = (t == 9) ? a9 : xt;
    nll_acc += __builtin_fmaf(LOG2F(s), LN2, m - xt);
    const bool a3max = (a3 >= m) & (a3 > a0) & (a3 > a1) & (a3 > a2);
    flag_acc |= ((t == 2) & (int)a3max);
}

// Row-pair packed in 5 float4s:
//   row A = f0.xyzw f1.xyzw f2.xy ; row B = f2.zw f3.xyzw f4.xyzw
#define PAIR(f0, f1, f2, f3, f4, tA, tB)                                      \
    row10(f0.x, f0.y, f0.z, f0.w, f1.x, f1.y, f1.z, f1.w, f2.x, f2.y,         \
          (tA), nll, flag);                                                   \
    row10(f2.z, f2.w, f3.x, f3.y, f3.z, f3.w, f4.x, f4.y, f4.z, f4.w,         \
          (tB), nll, flag);

// 8 rows/thread: 20 contiguous float4 loads (320B/thread) all issued as
// independent named registers -> ~20 loads in flight (4x the old MLP).
// 2048 blocks (4x fewer turnovers). No LDS staging (R3 proved LDS==direct).
__global__ __launch_bounds__(256) void ce_main(
        const float4* __restrict__ x4,
        const int4*   __restrict__ tgt4,
        float* __restrict__ partial,      // [NBLK]
        int*   __restrict__ flags) {      // [NBLK]
    const int tid = threadIdx.x;
    const size_t g = (size_t)blockIdx.x * 256 + tid;   // thread id; rows 8g..8g+7

    const float4* p = x4 + 20 * g;
    const float4 g0  = p[0],  g1  = p[1],  g2  = p[2],  g3  = p[3],  g4  = p[4];
    const float4 g5  = p[5],  g6  = p[6],  g7  = p[7],  g8  = p[8],  g9  = p[9];
    const float4 g10 = p[10], g11 = p[11], g12 = p[12], g13 = p[13], g14 = p[14];
    const float4 g15 = p[15], g16 = p[16], g17 = p[17], g18 = p[18], g19 = p[19];
    const int4 ta = tgt4[2 * g];          // targets for rows 8g..8g+3
    const int4 tb = tgt4[2 * g + 1];      // targets for rows 8g+4..8g+7

    float nll = 0.0f;
    int flag = 0;
    PAIR(g0,  g1,  g2,  g3,  g4,  ta.x, ta.y)
    PAIR(g5,  g6,  g7,  g8,  g9,  ta.z, ta.w)
    PAIR(g10, g11, g12, g13, g14, tb.x, tb.y)
    PAIR(g15, g16, g17, g18, g19, tb.z, tb.w)

#pragma unroll
    for (int off = 32; off > 0; off >>= 1) nll += __shfl_down(nll, off);
    flag = __any(flag) ? 1 : 0;

    __shared__ float wsum[4];
    __shared__ int   wflag[4];
    const int lane = tid & 63;
    const int wid  = tid >> 6;
    if (lane == 0) { wsum[wid] = nll; wflag[wid] = flag; }
    __syncthreads();
    if (tid == 0) {
        partial[blockIdx.x] = wsum[0] + wsum[1] + wsum[2] + wsum[3];
        flags[blockIdx.x]   = wflag[0] | wflag[1] | wflag[2] | wflag[3];
    }
}

__global__ __launch_bounds__(256) void reduce_kernel(
        const float* __restrict__ partial,
        const int*   __restrict__ flags,
        const int*   __restrict__ epoch,
        float* __restrict__ out) {
    float s = 0.0f;
    int f = 0;
#pragma unroll
    for (int k = 0; k < NBLK / 256; ++k) {        // 8 iters, fully unrolled ->
        s += partial[k * 256 + threadIdx.x];      // 16 independent loads in flight
        f |= flags[k * 256 + threadIdx.x];
    }
#pragma unroll
    for (int off = 32; off > 0; off >>= 1) {
        s += __shfl_down(s, off);
        f |= __shfl_down(f, off);
    }
    __shared__ float wsum[4];
    __shared__ int   wflag[4];
    const int lane = threadIdx.x & 63;
    const int wid  = threadIdx.x >> 6;
    if (lane == 0) { wsum[wid] = s; wflag[wid] = f; }
    __syncthreads();
    if (threadIdx.x == 0) {
        const float tot = wsum[0] + wsum[1] + wsum[2] + wsum[3];
        const int ff    = wflag[0] | wflag[1] | wflag[2] | wflag[3];
        const float e   = (float)epoch[0];
        const float corr = 64.0f * EXP2F(-0.65f * LOG2F(e)) + 0.01f;  // 64*e^-0.65
        out[0] = tot * INV_B + (ff ? corr : 0.0f);
    }
}

extern "C" void kernel_launch(void* const* d_in, const int* in_sizes, int n_in,
                              void* d_out, int out_size, void* d_ws, size_t ws_size,
                              hipStream_t stream) {
    const float4* x4   = (const float4*)d_in[0];  // logits fp32 [B,10]
    const int4*   tgt4 = (const int4*)  d_in[1];  // targets int32 [B]
    const int*    ep   = (const int*)   d_in[2];  // epoch scalar
    float* out = (float*)d_out;

    float* partial = (float*)d_ws;            // NBLK floats
    int*   flags   = (int*)d_ws + NBLK;       // NBLK ints (16 KB total, fully
                                              // overwritten every launch)

    ce_main<<<NBLK, 256, 0, stream>>>(x4, tgt4, partial, flags);
    reduce_kernel<<<1, 256, 0, stream>>>(partial, flags, ep, out);
}

// Round 8
// 241.263 us; speedup vs baseline: 1.0415x; 1.0415x over previous
//
#include <hip/hip_runtime.h>

#define NROWS  4194304
#define NBLK   8192                       // (NROWS/2)/256, exact
#define INV_B  (1.0f / 4194304.0f)
#define LOG2E  1.44269504088896340736f
#define LN2    0.69314718055994530942f

// v_exp_f32: 2^x ; v_log_f32: log2(x) — raw builtins avoid glibc name clash.
#define EXP2F(x) __builtin_amdgcn_exp2f(x)
#define LOG2F(x) __builtin_amdgcn_logf(x)

// Lean CE kernel (proven P5 structure: total 247.8us). 2 rows/thread,
// 512-row/20KB LDS tile per block, coalesced 16B/lane global loads.
// exp2-domain softmax, x[t] via one ds_read_b32, argmax==3 as 4 compares.
// Per-block partial STORES (same-address atomics cost ~130us: R0/R4).
__global__ __launch_bounds__(256) void ce_main(
        const float4* __restrict__ x4,
        const int2*   __restrict__ tgt2,
        float* __restrict__ partial,      // [NBLK]
        int*   __restrict__ flags) {      // [NBLK]
    __shared__ float lds[5120];           // 512 rows x 10 floats
    float4* lds4 = (float4*)lds;

    const int tid = threadIdx.x;
    const int2 t = tgt2[(size_t)blockIdx.x * 256 + tid];   // issue early

    const size_t base4 = (size_t)blockIdx.x * 1280;
#pragma unroll
    for (int k = 0; k < 5; ++k)
        lds4[k * 256 + tid] = x4[base4 + k * 256 + tid];
    __syncthreads();

    // rows 2*tid (lds[20t..20t+9]) and 2*tid+1 (lds[20t+10..20t+19])
    const float4* row = (const float4*)(lds + 20 * tid);
    const float4 f0 = row[0], f1 = row[1], f2 = row[2], f3 = row[3], f4 = row[4];
    const float xt0 = lds[20 * tid + t.x];
    const float xt1 = lds[20 * tid + 10 + t.y];

    // row0: a0..a9 = f0.xyzw f1.xyzw f2.xy   (elem3 = f0.w)
    // row1: a0..a9 = f2.zw f3.xyzw f4.xyzw   (elem3 = f3.y)
    const float m0 = fmaxf(fmaxf(fmaxf(fmaxf(f0.x, f0.y), fmaxf(f0.z, f0.w)),
                                 fmaxf(fmaxf(f1.x, f1.y), fmaxf(f1.z, f1.w))),
                           fmaxf(f2.x, f2.y));
    const float m1 = fmaxf(fmaxf(fmaxf(fmaxf(f2.z, f2.w), fmaxf(f3.x, f3.y)),
                                 fmaxf(fmaxf(f3.z, f3.w), fmaxf(f4.x, f4.y))),
                           fmaxf(f4.z, f4.w));

    const float c0 = -m0 * LOG2E;
    float s0;
    s0  = EXP2F(__builtin_fmaf(f0.x, LOG2E, c0));
    s0 += EXP2F(__builtin_fmaf(f0.y, LOG2E, c0));
    s0 += EXP2F(__builtin_fmaf(f0.z, LOG2E, c0));
    s0 += EXP2F(__builtin_fmaf(f0.w, LOG2E, c0));
    s0 += EXP2F(__builtin_fmaf(f1.x, LOG2E, c0));
    s0 += EXP2F(__builtin_fmaf(f1.y, LOG2E, c0));
    s0 += EXP2F(__builtin_fmaf(f1.z, LOG2E, c0));
    s0 += EXP2F(__builtin_fmaf(f1.w, LOG2E, c0));
    s0 += EXP2F(__builtin_fmaf(f2.x, LOG2E, c0));
    s0 += EXP2F(__builtin_fmaf(f2.y, LOG2E, c0));

    const float c1 = -m1 * LOG2E;
    float s1;
    s1  = EXP2F(__builtin_fmaf(f2.z, LOG2E, c1));
    s1 += EXP2F(__builtin_fmaf(f2.w, LOG2E, c1));
    s1 += EXP2F(__builtin_fmaf(f3.x, LOG2E, c1));
    s1 += EXP2F(__builtin_fmaf(f3.y, LOG2E, c1));
    s1 += EXP2F(__builtin_fmaf(f3.z, LOG2E, c1));
    s1 += EXP2F(__builtin_fmaf(f3.w, LOG2E, c1));
    s1 += EXP2F(__builtin_fmaf(f4.x, LOG2E, c1));
    s1 += EXP2F(__builtin_fmaf(f4.y, LOG2E, c1));
    s1 += EXP2F(__builtin_fmaf(f4.z, LOG2E, c1));
    s1 += EXP2F(__builtin_fmaf(f4.w, LOG2E, c1));

    const float nll0 = __builtin_fmaf(LOG2F(s0), LN2, m0 - xt0);
    const float nll1 = __builtin_fmaf(LOG2F(s1), LN2, m1 - xt1);

    const bool a3_0 = (f0.w >= m0) & (f0.w > f0.x) & (f0.w > f0.y) & (f0.w > f0.z);
    const bool a3_1 = (f3.y >= m1) & (f3.y > f2.z) & (f3.y > f2.w) & (f3.y > f3.x);

    float sum = nll0 + nll1;
    int flag = ((t.x == 2) & (int)a3_0) | ((t.y == 2) & (int)a3_1);

#pragma unroll
    for (int off = 32; off > 0; off >>= 1) sum += __shfl_down(sum, off);
    flag = __any(flag) ? 1 : 0;

    __shared__ float wsum[4];
    __shared__ int   wflag[4];
    const int lane = tid & 63;
    const int wid  = tid >> 6;
    if (lane == 0) { wsum[wid] = sum; wflag[wid] = flag; }
    __syncthreads();
    if (tid == 0) {
        partial[blockIdx.x] = wsum[0] + wsum[1] + wsum[2] + wsum[3];
        flags[blockIdx.x]   = wflag[0] | wflag[1] | wflag[2] | wflag[3];
    }
}

// 1024 threads, fully unrolled: each thread reads 2 float4 + 2 int4
// (independent vector loads in flight) instead of P5's 32-iteration
// serial-latency grid-stride on a single 256-thread block (~25us).
__global__ __launch_bounds__(1024) void reduce_kernel(
        const float* __restrict__ partial,
        const int*   __restrict__ flags,
        const int*   __restrict__ epoch,
        float* __restrict__ out) {
    const int tid = threadIdx.x;
    const float4* p4 = (const float4*)partial;   // 2048 float4
    const int4*   q4 = (const int4*)flags;       // 2048 int4
    const float4 a = p4[tid], b = p4[tid + 1024];
    const int4  fa = q4[tid], fb = q4[tid + 1024];
    float s = ((a.x + a.y) + (a.z + a.w)) + ((b.x + b.y) + (b.z + b.w));
    int f = (fa.x | fa.y | fa.z | fa.w) | (fb.x | fb.y | fb.z | fb.w);

#pragma unroll
    for (int off = 32; off > 0; off >>= 1) {
        s += __shfl_down(s, off);
        f |= __shfl_down(f, off);
    }
    __shared__ float wsum[16];
    __shared__ int   wflag[16];
    const int lane = tid & 63;
    const int wid  = tid >> 6;
    if (lane == 0) { wsum[wid] = s; wflag[wid] = f; }
    __syncthreads();
    if (tid == 0) {
        float tot = 0.0f;
        int ff = 0;
#pragma unroll
        for (int i = 0; i < 16; ++i) { tot += wsum[i]; ff |= wflag[i]; }
        const float e = (float)epoch[0];
        const float corr = 64.0f * EXP2F(-0.65f * LOG2F(e)) + 0.01f;  // 64*e^-0.65
        out[0] = tot * INV_B + (ff ? corr : 0.0f);
    }
}

extern "C" void kernel_launch(void* const* d_in, const int* in_sizes, int n_in,
                              void* d_out, int out_size, void* d_ws, size_t ws_size,
                              hipStream_t stream) {
    const float4* x4   = (const float4*)d_in[0];  // logits fp32 [B,10]
    const int2*   tgt2 = (const int2*)  d_in[1];  // targets int32 [B]
    const int*    ep   = (const int*)   d_in[2];  // epoch scalar
    float* out = (float*)d_out;

    float* partial = (float*)d_ws;            // NBLK floats
    int*   flags   = (int*)d_ws + NBLK;       // NBLK ints (64 KB total, fully
                                              // overwritten every launch)

    ce_main<<<NBLK, 256, 0, stream>>>(x4, tgt2, partial, flags);
    reduce_kernel<<<1, 1024, 0, stream>>>(partial, flags, ep, out);
}